// Round 1
// baseline (292.865 us; speedup 1.0000x reference)
//
#include <hip/hip_runtime.h>
#include <hip/hip_bf16.h>
#include <stdint.h>

// Problem constants (fixed by setup_inputs)
#define B_   8
#define S_   2048
#define C_   768
#define HID_ 768
#define H_   12
#define KW   9
#define D_   64
#define M_   (B_ * S_)   // 16384 rows
#define PADW 4           // KW/2
#define HK_  108         // H_*KW
#define NPAD 128         // padded N for GEMM2

typedef __attribute__((ext_vector_type(4))) float  floatx4;
typedef __attribute__((ext_vector_type(8))) __bf16 bf16x8;

#define GLD_LDS16(gptr, lptr)                                                  \
    __builtin_amdgcn_global_load_lds(                                          \
        (__attribute__((address_space(1))) void*)(gptr),                       \
        (__attribute__((address_space(3))) void*)(lptr), 16, 0, 0)

// ---------------------------------------------------------------------------
// Kernel 0: convert pw_weight and attn_W (zero-padded to 128 rows) to bf16
// ---------------------------------------------------------------------------
__global__ __launch_bounds__(256) void convert_w_kernel(
    const float* __restrict__ pwW, const float* __restrict__ attnW,
    __hip_bfloat16* __restrict__ pwWb, __hip_bfloat16* __restrict__ attnWb)
{
    int i = blockIdx.x * 256 + threadIdx.x;           // grid covers C_*HID_
    if (i < C_ * HID_) pwWb[i] = __float2bfloat16(pwW[i]);
    if (i < NPAD * HID_) {
        int n = i / HID_;
        float v = (n < HK_) ? attnW[i] : 0.0f;
        attnWb[i] = __float2bfloat16(v);
    }
}

// ---------------------------------------------------------------------------
// Kernel 1: depthwise conv1d (K=9, pad 4) over S, output bf16 [M_, HID_]
// one thread = one (m, 4 channels); float4 loads, 8B bf16x4 store
// ---------------------------------------------------------------------------
__global__ __launch_bounds__(256) void dwconv_kernel(
    const float* __restrict__ hidden, const float* __restrict__ dw_w,
    __hip_bfloat16* __restrict__ dw_out)
{
    int idx = blockIdx.x * 256 + threadIdx.x;  // [0, M_*(HID_/4))
    int hq = idx % (HID_ / 4);
    int m  = idx / (HID_ / 4);
    int s  = m & (S_ - 1);
    int bb = m - s;                            // b*S_
    int h  = hq * 4;

    float a0 = 0.f, a1 = 0.f, a2 = 0.f, a3 = 0.f;
#pragma unroll
    for (int k = 0; k < KW; ++k) {
        int sp = s + k - PADW;
        if ((unsigned)sp < (unsigned)S_) {
            const float4 x =
                *reinterpret_cast<const float4*>(&hidden[(size_t)(bb + sp) * HID_ + h]);
            a0 += x.x * dw_w[(h + 0) * KW + k];
            a1 += x.y * dw_w[(h + 1) * KW + k];
            a2 += x.z * dw_w[(h + 2) * KW + k];
            a3 += x.w * dw_w[(h + 3) * KW + k];
        }
    }
    union { __hip_bfloat16 b[4]; uint2 u; } o;
    o.b[0] = __float2bfloat16(a0);
    o.b[1] = __float2bfloat16(a1);
    o.b[2] = __float2bfloat16(a2);
    o.b[3] = __float2bfloat16(a3);
    *reinterpret_cast<uint2*>(&dw_out[(size_t)m * HID_ + h]) = o.u;
}

// ---------------------------------------------------------------------------
// GEMM: C[M,N] = A[M,K] * Bt[N,K]^T   (both row-major, K contiguous)
// m97 structure: 128x128 tile, BK=64, 4 waves (2x2 of 64x64), 16x16x32 MFMA,
// global_load_lds width 16 staging, linear LDS.
// MODE 0: epilogue  out_bf16 = (acc + bias[col]) * query[row,col]   (ld = C_)
// MODE 1: epilogue  out_f32  = acc                                  (ld = NPAD)
// ---------------------------------------------------------------------------
#define BM  128
#define BN  128
#define BKK 64

template <int MODE>
__global__ __launch_bounds__(256) void gemm_bt_kernel(
    const __hip_bfloat16* __restrict__ A,
    const __hip_bfloat16* __restrict__ Bt,
    const float* __restrict__ bias,      // MODE 0
    const float* __restrict__ query,     // MODE 0
    __hip_bfloat16* __restrict__ outB,   // MODE 0
    float* __restrict__ outF,            // MODE 1
    int ntN)
{
    __shared__ __align__(16) __hip_bfloat16 Alds[BM * BKK];
    __shared__ __align__(16) __hip_bfloat16 Blds[BN * BKK];

    const int t    = threadIdx.x;
    const int lane = t & 63;
    const int wave = t >> 6;
    const int wr   = wave >> 1, wc = wave & 1;
    const int l16  = lane & 15, lq = lane >> 4;

    const int tm   = (int)blockIdx.x / ntN;
    const int tn   = (int)blockIdx.x % ntN;
    const int row0 = tm * BM;
    const int col0 = tn * BN;

    const int K = HID_;  // 768

    floatx4 acc[4][4];
#pragma unroll
    for (int i = 0; i < 4; ++i)
#pragma unroll
        for (int j = 0; j < 4; ++j) acc[i][j] = (floatx4){0.f, 0.f, 0.f, 0.f};

    // staging coords: thread t stages 16B; iteration i covers rows [i*32,i*32+32)
    const int srow = t >> 3;        // 0..31
    const int scol = (t & 7) * 8;   // element offset within BK
    char* aBase = (char*)Alds + wave * 1024;   // wave-uniform LDS dest base
    char* bBase = (char*)Blds + wave * 1024;

    for (int kt = 0; kt < K; kt += BKK) {
#pragma unroll
        for (int i = 0; i < 4; ++i) {
            const __hip_bfloat16* ga = A  + (size_t)(row0 + i * 32 + srow) * K + kt + scol;
            const __hip_bfloat16* gb = Bt + (size_t)(col0 + i * 32 + srow) * K + kt + scol;
            GLD_LDS16(const_cast<__hip_bfloat16*>(ga), aBase + i * 4096);
            GLD_LDS16(const_cast<__hip_bfloat16*>(gb), bBase + i * 4096);
        }
        __syncthreads();   // compiler drains vmcnt before s_barrier

        const bf16x8* A8 = reinterpret_cast<const bf16x8*>(Alds);
        const bf16x8* B8 = reinterpret_cast<const bf16x8*>(Blds);
#pragma unroll
        for (int ks = 0; ks < 2; ++ks) {
            bf16x8 av[4], bv[4];
#pragma unroll
            for (int m = 0; m < 4; ++m)
                av[m] = A8[(wr * 64 + m * 16 + l16) * 8 + ks * 4 + lq];
#pragma unroll
            for (int n = 0; n < 4; ++n)
                bv[n] = B8[(wc * 64 + n * 16 + l16) * 8 + ks * 4 + lq];
#pragma unroll
            for (int m = 0; m < 4; ++m)
#pragma unroll
                for (int n = 0; n < 4; ++n)
                    acc[m][n] = __builtin_amdgcn_mfma_f32_16x16x32_bf16(
                        av[m], bv[n], acc[m][n], 0, 0, 0);
        }
        __syncthreads();
    }

    // epilogue — C/D layout: col = lane&15, row = (lane>>4)*4 + j  [m89-verified]
    const int orow0 = row0 + wr * 64;
    const int ocol0 = col0 + wc * 64;
#pragma unroll
    for (int m = 0; m < 4; ++m) {
#pragma unroll
        for (int n = 0; n < 4; ++n) {
            const int col = ocol0 + n * 16 + l16;
            if (MODE == 0) {
                const float bv = bias[col];
#pragma unroll
                for (int j = 0; j < 4; ++j) {
                    const int row = orow0 + m * 16 + lq * 4 + j;
                    float v = (acc[m][n][j] + bv) * query[(size_t)row * C_ + col];
                    outB[(size_t)row * C_ + col] = __float2bfloat16(v);
                }
            } else {
#pragma unroll
                for (int j = 0; j < 4; ++j) {
                    const int row = orow0 + m * 16 + lq * 4 + j;
                    outF[(size_t)row * NPAD + col] = acc[m][n][j];
                }
            }
        }
    }
}

// ---------------------------------------------------------------------------
// Kernel 4: double softmax over K=9 per (m, h); adds attn_b first
// ---------------------------------------------------------------------------
__global__ __launch_bounds__(256) void softmax2_kernel(
    const float* __restrict__ logits, const float* __restrict__ attn_b,
    float* __restrict__ filt)
{
    int r = blockIdx.x * 256 + threadIdx.x;   // [0, M_*H_)
    int h = r % H_;
    int m = r / H_;

    float v[KW];
#pragma unroll
    for (int k = 0; k < KW; ++k)
        v[k] = logits[(size_t)m * NPAD + h * KW + k] + attn_b[h * KW + k];

#pragma unroll
    for (int pass = 0; pass < 2; ++pass) {
        float mx = v[0];
#pragma unroll
        for (int k = 1; k < KW; ++k) mx = fmaxf(mx, v[k]);
        float s = 0.f;
#pragma unroll
        for (int k = 0; k < KW; ++k) { v[k] = __expf(v[k] - mx); s += v[k]; }
        float inv = 1.f / s;
#pragma unroll
        for (int k = 0; k < KW; ++k) v[k] *= inv;
    }
#pragma unroll
    for (int k = 0; k < KW; ++k) filt[(size_t)r * KW + k] = v[k];
}

// ---------------------------------------------------------------------------
// Kernel 5: light conv  out[m, h*64+d] = sum_k value[bb+s+k-4, h*64+d]*filt[r,k]
// one thread = one (m, h, d4): float4 over d
// ---------------------------------------------------------------------------
__global__ __launch_bounds__(256) void lightconv_kernel(
    const float* __restrict__ value, const float* __restrict__ filt,
    float* __restrict__ out)
{
    int idx = blockIdx.x * 256 + threadIdx.x;   // [0, M_*H_*16)
    int d4 = idx & 15;
    int r  = idx >> 4;          // m*H_ + h
    int h  = r % H_;
    int m  = r / H_;
    int s  = m & (S_ - 1);
    int bb = m - s;

    float f[KW];
#pragma unroll
    for (int k = 0; k < KW; ++k) f[k] = filt[(size_t)r * KW + k];

    float4 acc = {0.f, 0.f, 0.f, 0.f};
#pragma unroll
    for (int k = 0; k < KW; ++k) {
        int sp = s + k - PADW;
        if ((unsigned)sp < (unsigned)S_) {
            const float4 v = *reinterpret_cast<const float4*>(
                &value[(size_t)(bb + sp) * C_ + h * D_ + d4 * 4]);
            acc.x += v.x * f[k];
            acc.y += v.y * f[k];
            acc.z += v.z * f[k];
            acc.w += v.w * f[k];
        }
    }
    *reinterpret_cast<float4*>(&out[(size_t)m * C_ + h * D_ + d4 * 4]) = acc;
}

// ---------------------------------------------------------------------------
extern "C" void kernel_launch(void* const* d_in, const int* in_sizes, int n_in,
                              void* d_out, int out_size, void* d_ws, size_t ws_size,
                              hipStream_t stream)
{
    const float* query  = (const float*)d_in[0];
    const float* value  = (const float*)d_in[1];
    const float* hidden = (const float*)d_in[2];
    const float* dw_w   = (const float*)d_in[3];
    const float* pw_w   = (const float*)d_in[4];
    const float* sep_b  = (const float*)d_in[5];
    const float* attn_W = (const float*)d_in[6];
    const float* attn_b = (const float*)d_in[7];
    float* out = (float*)d_out;

    // workspace layout (all regions fully rewritten every call)
    char* ws = (char*)d_ws;
    __hip_bfloat16* dwb    = (__hip_bfloat16*)(ws);              // 25,165,824 B
    __hip_bfloat16* cab    = (__hip_bfloat16*)(ws + 25165824);   // 25,165,824 B
    __hip_bfloat16* pwWb   = (__hip_bfloat16*)(ws + 50331648);   //  1,179,648 B
    __hip_bfloat16* attnWb = (__hip_bfloat16*)(ws + 51511296);   //    196,608 B
    float*          logits = (float*)(ws + 51707904);            //  8,388,608 B
    float*          filt   = (float*)(ws + 60096512);            //  7,077,888 B
    // total: 67,174,400 B

    convert_w_kernel<<<(C_ * HID_) / 256, 256, 0, stream>>>(pw_w, attn_W, pwWb, attnWb);

    dwconv_kernel<<<(M_ * (HID_ / 4)) / 256, 256, 0, stream>>>(hidden, dw_w, dwb);

    gemm_bt_kernel<0><<<(M_ / BM) * (C_ / BN), 256, 0, stream>>>(
        dwb, pwWb, sep_b, query, cab, nullptr, C_ / BN);

    gemm_bt_kernel<1><<<(M_ / BM), 256, 0, stream>>>(
        cab, attnWb, nullptr, nullptr, nullptr, logits, 1);

    softmax2_kernel<<<(M_ * H_) / 256, 256, 0, stream>>>(logits, attn_b, filt);

    lightconv_kernel<<<(M_ * H_ * 16) / 256, 256, 0, stream>>>(value, filt, out);
}

// Round 2
// 122.766 us; speedup vs baseline: 2.3856x; 2.3856x over previous
//
#include <hip/hip_runtime.h>
#include <hip/hip_bf16.h>
#include <stdint.h>

// Problem constants (fixed by setup_inputs)
#define B_   8
#define S_   2048
#define C_   768
#define HID_ 768
#define H_   12
#define KW   9
#define D_   64
#define M_   (B_ * S_)   // 16384 rows
#define PADW 4           // KW/2
#define HK_  108         // H_*KW
#define NPAD 128         // padded N for GEMM2

typedef __attribute__((ext_vector_type(4))) float  floatx4;
typedef __attribute__((ext_vector_type(8))) __bf16 bf16x8;

#define GLD_LDS16(gptr, lptr)                                                  \
    __builtin_amdgcn_global_load_lds(                                          \
        (__attribute__((address_space(1))) void*)(gptr),                       \
        (__attribute__((address_space(3))) void*)(lptr), 16, 0, 0)

// ---------------------------------------------------------------------------
// Kernel 0: convert pw_weight and attn_W (zero-padded to 128 rows) to bf16
// ---------------------------------------------------------------------------
__global__ __launch_bounds__(256) void convert_w_kernel(
    const float* __restrict__ pwW, const float* __restrict__ attnW,
    __hip_bfloat16* __restrict__ pwWb, __hip_bfloat16* __restrict__ attnWb)
{
    int i = blockIdx.x * 256 + threadIdx.x;           // grid covers C_*HID_
    if (i < C_ * HID_) pwWb[i] = __float2bfloat16(pwW[i]);
    if (i < NPAD * HID_) {
        int n = i / HID_;
        float v = (n < HK_) ? attnW[i] : 0.0f;
        attnWb[i] = __float2bfloat16(v);
    }
}

// ---------------------------------------------------------------------------
// Kernel 1: depthwise conv1d (K=9, pad 4), sliding-window version.
// Thread owns 4 channels (h..h+3) x TSD consecutive s. Weights: 9 aligned
// float4 loads (36 floats, base byte 144*hq is 16B-aligned). Hidden rows
// slide through a 9-deep float4 register window: 24 loads per 16 outputs.
// ---------------------------------------------------------------------------
#define TSD 16

__global__ __launch_bounds__(256) void dwconv_kernel(
    const float* __restrict__ hidden, const float* __restrict__ dw_w,
    __hip_bfloat16* __restrict__ dw_out)
{
    int idx  = blockIdx.x * 256 + threadIdx.x;   // [0, 196608)
    int hq   = idx % (HID_ / 4);                 // 0..191
    int rest = idx / (HID_ / 4);                 // 0..1023
    int sc   = rest % (S_ / TSD);                // 0..127
    int b    = rest / (S_ / TSD);                // 0..7
    int h    = hq * 4;
    int s0   = sc * TSD;
    size_t base = (size_t)b * S_ * HID_ + h;     // row-0 addr for this (b, h)

    // 36 consecutive weight floats, 16B-aligned (144*hq bytes)
    float w[36];
    const float4* wp = reinterpret_cast<const float4*>(dw_w + (size_t)h * KW);
#pragma unroll
    for (int i = 0; i < 9; ++i) {
        float4 t = wp[i];
        w[4 * i + 0] = t.x; w[4 * i + 1] = t.y;
        w[4 * i + 2] = t.z; w[4 * i + 3] = t.w;
    }

    float4 win[KW];
#pragma unroll
    for (int k = 0; k < 8; ++k) {
        int sp = s0 + k - PADW;
        float4 v = {0.f, 0.f, 0.f, 0.f};
        if ((unsigned)sp < (unsigned)S_)
            v = *reinterpret_cast<const float4*>(&hidden[base + (size_t)sp * HID_]);
        win[k] = v;
    }

#pragma unroll
    for (int i = 0; i < TSD; ++i) {
        int sp = s0 + i + PADW;
        float4 nv = {0.f, 0.f, 0.f, 0.f};
        if ((unsigned)sp < (unsigned)S_)
            nv = *reinterpret_cast<const float4*>(&hidden[base + (size_t)sp * HID_]);
        win[8] = nv;

        float a0 = 0.f, a1 = 0.f, a2 = 0.f, a3 = 0.f;
#pragma unroll
        for (int k = 0; k < KW; ++k) {
            a0 += win[k].x * w[k];
            a1 += win[k].y * w[9 + k];
            a2 += win[k].z * w[18 + k];
            a3 += win[k].w * w[27 + k];
        }
        union { __hip_bfloat16 bv[4]; uint2 u; } o;
        o.bv[0] = __float2bfloat16(a0);
        o.bv[1] = __float2bfloat16(a1);
        o.bv[2] = __float2bfloat16(a2);
        o.bv[3] = __float2bfloat16(a3);
        *reinterpret_cast<uint2*>(&dw_out[base + (size_t)(s0 + i) * HID_]) = o.u;

#pragma unroll
        for (int k = 0; k < 8; ++k) win[k] = win[k + 1];
    }
}

// ---------------------------------------------------------------------------
// GEMM: C[M,N] = A[M,K] * Bt[N,K]^T   (both row-major, K contiguous)
// m97 structure: 128x128 tile, BK=64, 4 waves (2x2 of 64x64), 16x16x32 MFMA,
// global_load_lds width 16 staging, linear LDS.
// MODE 0: epilogue  out_bf16 = (acc + bias[col]) * query[row,col]   (ld = C_)
// MODE 1: epilogue  out_f32  = acc                                  (ld = NPAD)
// ---------------------------------------------------------------------------
#define BM  128
#define BN  128
#define BKK 64

template <int MODE>
__global__ __launch_bounds__(256) void gemm_bt_kernel(
    const __hip_bfloat16* __restrict__ A,
    const __hip_bfloat16* __restrict__ Bt,
    const float* __restrict__ bias,      // MODE 0
    const float* __restrict__ query,     // MODE 0
    __hip_bfloat16* __restrict__ outB,   // MODE 0
    float* __restrict__ outF,            // MODE 1
    int ntN)
{
    __shared__ __align__(16) __hip_bfloat16 Alds[BM * BKK];
    __shared__ __align__(16) __hip_bfloat16 Blds[BN * BKK];

    const int t    = threadIdx.x;
    const int lane = t & 63;
    const int wave = t >> 6;
    const int wr   = wave >> 1, wc = wave & 1;
    const int l16  = lane & 15, lq = lane >> 4;

    const int tm   = (int)blockIdx.x / ntN;
    const int tn   = (int)blockIdx.x % ntN;
    const int row0 = tm * BM;
    const int col0 = tn * BN;

    const int K = HID_;  // 768

    floatx4 acc[4][4];
#pragma unroll
    for (int i = 0; i < 4; ++i)
#pragma unroll
        for (int j = 0; j < 4; ++j) acc[i][j] = (floatx4){0.f, 0.f, 0.f, 0.f};

    // staging coords: thread t stages 16B; iteration i covers rows [i*32,i*32+32)
    const int srow = t >> 3;        // 0..31
    const int scol = (t & 7) * 8;   // element offset within BK
    char* aBase = (char*)Alds + wave * 1024;   // wave-uniform LDS dest base
    char* bBase = (char*)Blds + wave * 1024;

    for (int kt = 0; kt < K; kt += BKK) {
#pragma unroll
        for (int i = 0; i < 4; ++i) {
            const __hip_bfloat16* ga = A  + (size_t)(row0 + i * 32 + srow) * K + kt + scol;
            const __hip_bfloat16* gb = Bt + (size_t)(col0 + i * 32 + srow) * K + kt + scol;
            GLD_LDS16(const_cast<__hip_bfloat16*>(ga), aBase + i * 4096);
            GLD_LDS16(const_cast<__hip_bfloat16*>(gb), bBase + i * 4096);
        }
        __syncthreads();   // compiler drains vmcnt before s_barrier

        const bf16x8* A8 = reinterpret_cast<const bf16x8*>(Alds);
        const bf16x8* B8 = reinterpret_cast<const bf16x8*>(Blds);
#pragma unroll
        for (int ks = 0; ks < 2; ++ks) {
            bf16x8 av[4], bv[4];
#pragma unroll
            for (int m = 0; m < 4; ++m)
                av[m] = A8[(wr * 64 + m * 16 + l16) * 8 + ks * 4 + lq];
#pragma unroll
            for (int n = 0; n < 4; ++n)
                bv[n] = B8[(wc * 64 + n * 16 + l16) * 8 + ks * 4 + lq];
#pragma unroll
            for (int m = 0; m < 4; ++m)
#pragma unroll
                for (int n = 0; n < 4; ++n)
                    acc[m][n] = __builtin_amdgcn_mfma_f32_16x16x32_bf16(
                        av[m], bv[n], acc[m][n], 0, 0, 0);
        }
        __syncthreads();
    }

    // epilogue — C/D layout: col = lane&15, row = (lane>>4)*4 + j  [m89-verified]
    const int orow0 = row0 + wr * 64;
    const int ocol0 = col0 + wc * 64;
#pragma unroll
    for (int m = 0; m < 4; ++m) {
#pragma unroll
        for (int n = 0; n < 4; ++n) {
            const int col = ocol0 + n * 16 + l16;
            if (MODE == 0) {
                const float bv = bias[col];
#pragma unroll
                for (int j = 0; j < 4; ++j) {
                    const int row = orow0 + m * 16 + lq * 4 + j;
                    float v = (acc[m][n][j] + bv) * query[(size_t)row * C_ + col];
                    outB[(size_t)row * C_ + col] = __float2bfloat16(v);
                }
            } else {
#pragma unroll
                for (int j = 0; j < 4; ++j) {
                    const int row = orow0 + m * 16 + lq * 4 + j;
                    outF[(size_t)row * NPAD + col] = acc[m][n][j];
                }
            }
        }
    }
}

// ---------------------------------------------------------------------------
// Kernel 4: double softmax over K=9 per (m, h); adds attn_b first
// ---------------------------------------------------------------------------
__global__ __launch_bounds__(256) void softmax2_kernel(
    const float* __restrict__ logits, const float* __restrict__ attn_b,
    float* __restrict__ filt)
{
    int r = blockIdx.x * 256 + threadIdx.x;   // [0, M_*H_)
    int h = r % H_;
    int m = r / H_;

    float v[KW];
#pragma unroll
    for (int k = 0; k < KW; ++k)
        v[k] = logits[(size_t)m * NPAD + h * KW + k] + attn_b[h * KW + k];

#pragma unroll
    for (int pass = 0; pass < 2; ++pass) {
        float mx = v[0];
#pragma unroll
        for (int k = 1; k < KW; ++k) mx = fmaxf(mx, v[k]);
        float s = 0.f;
#pragma unroll
        for (int k = 0; k < KW; ++k) { v[k] = __expf(v[k] - mx); s += v[k]; }
        float inv = 1.f / s;
#pragma unroll
        for (int k = 0; k < KW; ++k) v[k] *= inv;
    }
#pragma unroll
    for (int k = 0; k < KW; ++k) filt[(size_t)r * KW + k] = v[k];
}

// ---------------------------------------------------------------------------
// Kernel 5: light conv, sliding-window version.
// Block owns (b, h, 256-s superchunk). filt rows (256 s x 9) staged in LDS.
// Thread = (d4, s-group of 16): 9-deep float4 window over value rows.
// VMEM/thread: 24 value + 9 filt-stage + 16 stores per 16 float4 outputs.
// ---------------------------------------------------------------------------
#define TSL 16
#define SCHK 256   // s per block (16 s-groups x TSL)

__global__ __launch_bounds__(256) void lightconv_kernel(
    const float* __restrict__ value, const float* __restrict__ filt,
    float* __restrict__ out)
{
    __shared__ float fl[SCHK * KW];   // 2304 floats

    const int tid = threadIdx.x;
    const int blk = blockIdx.x;                   // [0, 768)
    const int nSC = S_ / SCHK;                    // 8
    const int b   = blk / (H_ * nSC);
    const int rem = blk % (H_ * nSC);
    const int h   = rem / nSC;
    const int sch = rem % nSC;
    const int S0  = sch * SCHK;

    // stage filt: 2304 consecutive-in-(s,k) values; fl[j] with j = so*9+k
    {
        const size_t r0 = ((size_t)b * S_ + S0) * H_ + h;   // filt row of s=S0
#pragma unroll
        for (int i = 0; i < 9; ++i) {
            int j  = tid + 256 * i;               // 0..2303
            int so = j / KW;
            int k  = j - so * KW;
            fl[j] = filt[(r0 + (size_t)so * H_) * KW + k];
        }
    }
    __syncthreads();

    const int d4 = tid & 15;
    const int sg = tid >> 4;                      // 0..15
    const int s0 = S0 + sg * TSL;
    const size_t vbase = (size_t)b * S_ * C_ + h * D_ + d4 * 4;
    const float* flrow = &fl[(sg * TSL) * KW];

    float4 win[KW];
#pragma unroll
    for (int k = 0; k < 8; ++k) {
        int sp = s0 + k - PADW;
        float4 v = {0.f, 0.f, 0.f, 0.f};
        if ((unsigned)sp < (unsigned)S_)
            v = *reinterpret_cast<const float4*>(&value[vbase + (size_t)sp * C_]);
        win[k] = v;
    }

#pragma unroll
    for (int i = 0; i < TSL; ++i) {
        int sp = s0 + i + PADW;
        float4 nv = {0.f, 0.f, 0.f, 0.f};
        if ((unsigned)sp < (unsigned)S_)
            nv = *reinterpret_cast<const float4*>(&value[vbase + (size_t)sp * C_]);
        win[8] = nv;

        float4 acc = {0.f, 0.f, 0.f, 0.f};
#pragma unroll
        for (int k = 0; k < KW; ++k) {
            float f = flrow[i * KW + k];
            acc.x += win[k].x * f;
            acc.y += win[k].y * f;
            acc.z += win[k].z * f;
            acc.w += win[k].w * f;
        }
        *reinterpret_cast<float4*>(&out[vbase + (size_t)(s0 + i) * C_]) = acc;

#pragma unroll
        for (int k = 0; k < 8; ++k) win[k] = win[k + 1];
    }
}

// ---------------------------------------------------------------------------
extern "C" void kernel_launch(void* const* d_in, const int* in_sizes, int n_in,
                              void* d_out, int out_size, void* d_ws, size_t ws_size,
                              hipStream_t stream)
{
    const float* query  = (const float*)d_in[0];
    const float* value  = (const float*)d_in[1];
    const float* hidden = (const float*)d_in[2];
    const float* dw_w   = (const float*)d_in[3];
    const float* pw_w   = (const float*)d_in[4];
    const float* sep_b  = (const float*)d_in[5];
    const float* attn_W = (const float*)d_in[6];
    const float* attn_b = (const float*)d_in[7];
    float* out = (float*)d_out;

    // workspace layout (all regions fully rewritten every call)
    char* ws = (char*)d_ws;
    __hip_bfloat16* dwb    = (__hip_bfloat16*)(ws);              // 25,165,824 B
    __hip_bfloat16* cab    = (__hip_bfloat16*)(ws + 25165824);   // 25,165,824 B
    __hip_bfloat16* pwWb   = (__hip_bfloat16*)(ws + 50331648);   //  1,179,648 B
    __hip_bfloat16* attnWb = (__hip_bfloat16*)(ws + 51511296);   //    196,608 B
    float*          logits = (float*)(ws + 51707904);            //  8,388,608 B
    float*          filt   = (float*)(ws + 60096512);            //  7,077,888 B
    // total: 67,174,400 B

    convert_w_kernel<<<(C_ * HID_) / 256, 256, 0, stream>>>(pw_w, attn_W, pwWb, attnWb);

    dwconv_kernel<<<(M_ * (HID_ / 4)) / (256 * TSD), 256, 0, stream>>>(hidden, dw_w, dwb);

    gemm_bt_kernel<0><<<(M_ / BM) * (C_ / BN), 256, 0, stream>>>(
        dwb, pwWb, sep_b, query, cab, nullptr, C_ / BN);

    gemm_bt_kernel<1><<<(M_ / BM), 256, 0, stream>>>(
        cab, attnWb, nullptr, nullptr, nullptr, logits, 1);

    softmax2_kernel<<<(M_ * H_) / 256, 256, 0, stream>>>(logits, attn_b, filt);

    lightconv_kernel<<<B_ * H_ * (S_ / SCHK), 256, 0, stream>>>(value, filt, out);
}

// Round 3
// 106.592 us; speedup vs baseline: 2.7475x; 1.1517x over previous
//
#include <hip/hip_runtime.h>
#include <hip/hip_bf16.h>
#include <stdint.h>

// Problem constants (fixed by setup_inputs)
#define B_   8
#define S_   2048
#define C_   768
#define HID_ 768
#define H_   12
#define KW   9
#define D_   64
#define M_   (B_ * S_)   // 16384 rows
#define PADW 4           // KW/2
#define HK_  108         // H_*KW
#define NPAD 128         // padded N for GEMM2

typedef __attribute__((ext_vector_type(4))) float  floatx4;
typedef __attribute__((ext_vector_type(8))) __bf16 bf16x8;

#define GLD_LDS16(gptr, lptr)                                                  \
    __builtin_amdgcn_global_load_lds(                                          \
        (__attribute__((address_space(1))) void*)(gptr),                       \
        (__attribute__((address_space(3))) void*)(lptr), 16, 0, 0)

// ---------------------------------------------------------------------------
// Kernel 0: convert pw_weight and attn_W (zero-padded to 128 rows) to bf16
// ---------------------------------------------------------------------------
__global__ __launch_bounds__(256) void convert_w_kernel(
    const float* __restrict__ pwW, const float* __restrict__ attnW,
    __hip_bfloat16* __restrict__ pwWb, __hip_bfloat16* __restrict__ attnWb)
{
    int i = blockIdx.x * 256 + threadIdx.x;           // grid covers C_*HID_
    if (i < C_ * HID_) pwWb[i] = __float2bfloat16(pwW[i]);
    if (i < NPAD * HID_) {
        int n = i / HID_;
        float v = (n < HK_) ? attnW[i] : 0.0f;
        attnWb[i] = __float2bfloat16(v);
    }
}

// ---------------------------------------------------------------------------
// Kernel 1: depthwise conv1d (K=9, pad 4), sliding-window version.
// ---------------------------------------------------------------------------
#define TSD 16

__global__ __launch_bounds__(256) void dwconv_kernel(
    const float* __restrict__ hidden, const float* __restrict__ dw_w,
    __hip_bfloat16* __restrict__ dw_out)
{
    int idx  = blockIdx.x * 256 + threadIdx.x;   // [0, 196608)
    int hq   = idx % (HID_ / 4);                 // 0..191
    int rest = idx / (HID_ / 4);                 // 0..1023
    int sc   = rest % (S_ / TSD);                // 0..127
    int b    = rest / (S_ / TSD);                // 0..7
    int h    = hq * 4;
    int s0   = sc * TSD;
    size_t base = (size_t)b * S_ * HID_ + h;     // row-0 addr for this (b, h)

    float w[36];
    const float4* wp = reinterpret_cast<const float4*>(dw_w + (size_t)h * KW);
#pragma unroll
    for (int i = 0; i < 9; ++i) {
        float4 t = wp[i];
        w[4 * i + 0] = t.x; w[4 * i + 1] = t.y;
        w[4 * i + 2] = t.z; w[4 * i + 3] = t.w;
    }

    float4 win[KW];
#pragma unroll
    for (int k = 0; k < 8; ++k) {
        int sp = s0 + k - PADW;
        float4 v = {0.f, 0.f, 0.f, 0.f};
        if ((unsigned)sp < (unsigned)S_)
            v = *reinterpret_cast<const float4*>(&hidden[base + (size_t)sp * HID_]);
        win[k] = v;
    }

#pragma unroll
    for (int i = 0; i < TSD; ++i) {
        int sp = s0 + i + PADW;
        float4 nv = {0.f, 0.f, 0.f, 0.f};
        if ((unsigned)sp < (unsigned)S_)
            nv = *reinterpret_cast<const float4*>(&hidden[base + (size_t)sp * HID_]);
        win[8] = nv;

        float a0 = 0.f, a1 = 0.f, a2 = 0.f, a3 = 0.f;
#pragma unroll
        for (int k = 0; k < KW; ++k) {
            a0 += win[k].x * w[k];
            a1 += win[k].y * w[9 + k];
            a2 += win[k].z * w[18 + k];
            a3 += win[k].w * w[27 + k];
        }
        union { __hip_bfloat16 bv[4]; uint2 u; } o;
        o.bv[0] = __float2bfloat16(a0);
        o.bv[1] = __float2bfloat16(a1);
        o.bv[2] = __float2bfloat16(a2);
        o.bv[3] = __float2bfloat16(a3);
        *reinterpret_cast<uint2*>(&dw_out[base + (size_t)(s0 + i) * HID_]) = o.u;

#pragma unroll
        for (int k = 0; k < 8; ++k) win[k] = win[k + 1];
    }
}

// ---------------------------------------------------------------------------
// GEMM: C[M,N] = A[M,K] * Bt[N,K]^T   (both row-major, K contiguous)
// m97 structure, retiled for occupancy at this shape: TBM x 64 tile, BK=64,
// 4 waves (2x2, per-wave TBM/2 x 32), 16x16x32 MFMA, global_load_lds w16.
// Grid = (M/TBM)*(N/64); XCD-chunked swizzle keeps one tm-panel per XCD L2.
// MODE 0: out_bf16 = (acc + bias[col]) * query[row,col]   (ld = C_)
// MODE 1: out_f32  = acc                                  (ld = NPAD)
// ---------------------------------------------------------------------------
#define BKK 64

template <int MODE, int TBM>
__global__ __launch_bounds__(256) void gemm_bt_kernel(
    const __hip_bfloat16* __restrict__ A,
    const __hip_bfloat16* __restrict__ Bt,
    const float* __restrict__ bias,      // MODE 0
    const float* __restrict__ query,     // MODE 0
    __hip_bfloat16* __restrict__ outB,   // MODE 0
    float* __restrict__ outF,            // MODE 1
    int ntN)
{
    constexpr int MF = TBM / 32;         // A m-frags per wave (4 or 2)
    __shared__ __align__(16) __hip_bfloat16 Alds[TBM * BKK];
    __shared__ __align__(16) __hip_bfloat16 Blds[64 * BKK];

    const int t    = threadIdx.x;
    const int lane = t & 63;
    const int wave = t >> 6;
    const int wr   = wave >> 1, wc = wave & 1;
    const int l16  = lane & 15, lq = lane >> 4;

    // XCD-chunked bijective swizzle (gridDim.x % 8 == 0)
    const int nwg  = (int)gridDim.x;
    const int chunk = nwg >> 3;
    const int wg   = ((int)blockIdx.x & 7) * chunk + ((int)blockIdx.x >> 3);

    const int tm   = wg / ntN;
    const int tn   = wg % ntN;
    const int row0 = tm * TBM;
    const int col0 = tn * 64;

    const int K = HID_;  // 768

    floatx4 acc[MF][2];
#pragma unroll
    for (int i = 0; i < MF; ++i)
#pragma unroll
        for (int j = 0; j < 2; ++j) acc[i][j] = (floatx4){0.f, 0.f, 0.f, 0.f};

    // staging coords: thread t stages 16B; instr i covers rows [i*32, i*32+32)
    const int srow = t >> 3;        // 0..31
    const int scol = (t & 7) * 8;   // element offset within BK
    char* aBase = (char*)Alds + wave * 1024;   // wave-uniform LDS dest base
    char* bBase = (char*)Blds + wave * 1024;

    for (int kt = 0; kt < K; kt += BKK) {
#pragma unroll
        for (int i = 0; i < MF; ++i) {
            const __hip_bfloat16* ga = A + (size_t)(row0 + i * 32 + srow) * K + kt + scol;
            GLD_LDS16(const_cast<__hip_bfloat16*>(ga), aBase + i * 4096);
        }
#pragma unroll
        for (int i = 0; i < 2; ++i) {
            const __hip_bfloat16* gb = Bt + (size_t)(col0 + i * 32 + srow) * K + kt + scol;
            GLD_LDS16(const_cast<__hip_bfloat16*>(gb), bBase + i * 4096);
        }
        __syncthreads();   // compiler drains vmcnt before s_barrier

        const bf16x8* A8 = reinterpret_cast<const bf16x8*>(Alds);
        const bf16x8* B8 = reinterpret_cast<const bf16x8*>(Blds);
#pragma unroll
        for (int ks = 0; ks < 2; ++ks) {
            bf16x8 av[MF], bv[2];
#pragma unroll
            for (int m = 0; m < MF; ++m)
                av[m] = A8[(wr * (TBM / 2) + m * 16 + l16) * 8 + ks * 4 + lq];
#pragma unroll
            for (int n = 0; n < 2; ++n)
                bv[n] = B8[(wc * 32 + n * 16 + l16) * 8 + ks * 4 + lq];
#pragma unroll
            for (int m = 0; m < MF; ++m)
#pragma unroll
                for (int n = 0; n < 2; ++n)
                    acc[m][n] = __builtin_amdgcn_mfma_f32_16x16x32_bf16(
                        av[m], bv[n], acc[m][n], 0, 0, 0);
        }
        __syncthreads();
    }

    // epilogue — C/D layout: col = lane&15, row = (lane>>4)*4 + j  [m89]
    const int orow0 = row0 + wr * (TBM / 2);
    const int ocol0 = col0 + wc * 32;
#pragma unroll
    for (int m = 0; m < MF; ++m) {
#pragma unroll
        for (int n = 0; n < 2; ++n) {
            const int col = ocol0 + n * 16 + l16;
            if (MODE == 0) {
                const float bv = bias[col];
#pragma unroll
                for (int j = 0; j < 4; ++j) {
                    const int row = orow0 + m * 16 + lq * 4 + j;
                    float v = (acc[m][n][j] + bv) * query[(size_t)row * C_ + col];
                    outB[(size_t)row * C_ + col] = __float2bfloat16(v);
                }
            } else {
#pragma unroll
                for (int j = 0; j < 4; ++j) {
                    const int row = orow0 + m * 16 + lq * 4 + j;
                    outF[(size_t)row * NPAD + col] = acc[m][n][j];
                }
            }
        }
    }
}

// ---------------------------------------------------------------------------
// Kernel 4: double softmax over K=9 per (m, h); adds attn_b first
// ---------------------------------------------------------------------------
__global__ __launch_bounds__(256) void softmax2_kernel(
    const float* __restrict__ logits, const float* __restrict__ attn_b,
    float* __restrict__ filt)
{
    int r = blockIdx.x * 256 + threadIdx.x;   // [0, M_*H_)
    int h = r % H_;
    int m = r / H_;

    float v[KW];
#pragma unroll
    for (int k = 0; k < KW; ++k)
        v[k] = logits[(size_t)m * NPAD + h * KW + k] + attn_b[h * KW + k];

#pragma unroll
    for (int pass = 0; pass < 2; ++pass) {
        float mx = v[0];
#pragma unroll
        for (int k = 1; k < KW; ++k) mx = fmaxf(mx, v[k]);
        float s = 0.f;
#pragma unroll
        for (int k = 0; k < KW; ++k) { v[k] = __expf(v[k] - mx); s += v[k]; }
        float inv = 1.f / s;
#pragma unroll
        for (int k = 0; k < KW; ++k) v[k] *= inv;
    }
#pragma unroll
    for (int k = 0; k < KW; ++k) filt[(size_t)r * KW + k] = v[k];
}

// ---------------------------------------------------------------------------
// Kernel 5: light conv, sliding-window version.
// ---------------------------------------------------------------------------
#define TSL 16
#define SCHK 256   // s per block (16 s-groups x TSL)

__global__ __launch_bounds__(256) void lightconv_kernel(
    const float* __restrict__ value, const float* __restrict__ filt,
    float* __restrict__ out)
{
    __shared__ float fl[SCHK * KW];   // 2304 floats

    const int tid = threadIdx.x;
    const int blk = blockIdx.x;                   // [0, 768)
    const int nSC = S_ / SCHK;                    // 8
    const int b   = blk / (H_ * nSC);
    const int rem = blk % (H_ * nSC);
    const int h   = rem / nSC;
    const int sch = rem % nSC;
    const int S0  = sch * SCHK;

    {
        const size_t r0 = ((size_t)b * S_ + S0) * H_ + h;   // filt row of s=S0
#pragma unroll
        for (int i = 0; i < 9; ++i) {
            int j  = tid + 256 * i;               // 0..2303
            int so = j / KW;
            int k  = j - so * KW;
            fl[j] = filt[(r0 + (size_t)so * H_) * KW + k];
        }
    }
    __syncthreads();

    const int d4 = tid & 15;
    const int sg = tid >> 4;                      // 0..15
    const int s0 = S0 + sg * TSL;
    const size_t vbase = (size_t)b * S_ * C_ + h * D_ + d4 * 4;
    const float* flrow = &fl[(sg * TSL) * KW];

    float4 win[KW];
#pragma unroll
    for (int k = 0; k < 8; ++k) {
        int sp = s0 + k - PADW;
        float4 v = {0.f, 0.f, 0.f, 0.f};
        if ((unsigned)sp < (unsigned)S_)
            v = *reinterpret_cast<const float4*>(&value[vbase + (size_t)sp * C_]);
        win[k] = v;
    }

#pragma unroll
    for (int i = 0; i < TSL; ++i) {
        int sp = s0 + i + PADW;
        float4 nv = {0.f, 0.f, 0.f, 0.f};
        if ((unsigned)sp < (unsigned)S_)
            nv = *reinterpret_cast<const float4*>(&value[vbase + (size_t)sp * C_]);
        win[8] = nv;

        float4 acc = {0.f, 0.f, 0.f, 0.f};
#pragma unroll
        for (int k = 0; k < KW; ++k) {
            float f = flrow[i * KW + k];
            acc.x += win[k].x * f;
            acc.y += win[k].y * f;
            acc.z += win[k].z * f;
            acc.w += win[k].w * f;
        }
        *reinterpret_cast<float4*>(&out[vbase + (size_t)(s0 + i) * C_]) = acc;

#pragma unroll
        for (int k = 0; k < 8; ++k) win[k] = win[k + 1];
    }
}

// ---------------------------------------------------------------------------
extern "C" void kernel_launch(void* const* d_in, const int* in_sizes, int n_in,
                              void* d_out, int out_size, void* d_ws, size_t ws_size,
                              hipStream_t stream)
{
    const float* query  = (const float*)d_in[0];
    const float* value  = (const float*)d_in[1];
    const float* hidden = (const float*)d_in[2];
    const float* dw_w   = (const float*)d_in[3];
    const float* pw_w   = (const float*)d_in[4];
    const float* sep_b  = (const float*)d_in[5];
    const float* attn_W = (const float*)d_in[6];
    const float* attn_b = (const float*)d_in[7];
    float* out = (float*)d_out;

    // workspace layout (all regions fully rewritten every call)
    char* ws = (char*)d_ws;
    __hip_bfloat16* dwb    = (__hip_bfloat16*)(ws);              // 25,165,824 B
    __hip_bfloat16* cab    = (__hip_bfloat16*)(ws + 25165824);   // 25,165,824 B
    __hip_bfloat16* pwWb   = (__hip_bfloat16*)(ws + 50331648);   //  1,179,648 B
    __hip_bfloat16* attnWb = (__hip_bfloat16*)(ws + 51511296);   //    196,608 B
    float*          logits = (float*)(ws + 51707904);            //  8,388,608 B
    float*          filt   = (float*)(ws + 60096512);            //  7,077,888 B
    // total: 67,174,400 B

    convert_w_kernel<<<(C_ * HID_) / 256, 256, 0, stream>>>(pw_w, attn_W, pwWb, attnWb);

    dwconv_kernel<<<(M_ * (HID_ / 4)) / (256 * TSD), 256, 0, stream>>>(hidden, dw_w, dwb);

    // GEMM1: 128x64 tiles -> 128*12 = 1536 blocks (6/CU)
    gemm_bt_kernel<0, 128><<<(M_ / 128) * (C_ / 64), 256, 0, stream>>>(
        dwb, pwWb, sep_b, query, cab, nullptr, C_ / 64);

    // GEMM2: 64x64 tiles -> 256*2 = 512 blocks (2/CU)
    gemm_bt_kernel<1, 64><<<(M_ / 64) * (NPAD / 64), 256, 0, stream>>>(
        cab, attnWb, nullptr, nullptr, nullptr, logits, NPAD / 64);

    softmax2_kernel<<<(M_ * H_) / 256, 256, 0, stream>>>(logits, attn_b, filt);

    lightconv_kernel<<<B_ * H_ * (S_ / SCHK), 256, 0, stream>>>(value, filt, out);
}